// Round 5
// baseline (962.548 us; speedup 1.0000x reference)
//
#include <hip/hip_runtime.h>
#include <stdint.h>

#define SEQ      1024
#define NT       128
#define NBATCH   256
#define RING     4
#define SLOT_F32 (64 * 36)   // per-slot: 64 lanes x (32 floats + 4 pad)

typedef float f32x4v __attribute__((ext_vector_type(4)));
using short8 = __attribute__((ext_vector_type(8))) short;
union B8 { uint4 u4; short8 s8; };

// blocks 0..15: recurrence (16 batches each; wave0 = consumer, waves1-3 = producers)
// blocks 16..79: score gathers (4 batches each, 1 wave per batch)
__global__ __launch_bounds__(256, 1) void crf_kernel(
    const float* __restrict__ emissions,   // [B, SEQ, NT]
    const float* __restrict__ transitions, // [NT, NT]
    const int*   __restrict__ tags,        // [B, SEQ]
    const float* __restrict__ mask,        // [B, SEQ]
    float* __restrict__ out)               // [1]
{
    const int blk = blockIdx.x;
    const int tid = threadIdx.x;

    if (blk >= 16) {
        // ---------------- score blocks ----------------
        int b    = (blk - 16) * 4 + (tid >> 6);
        int lane = tid & 63;
        const float* emb = emissions + (size_t)b * SEQ * NT;
        const int*   tgb = tags + (size_t)b * SEQ;
        const float* mkb = mask + (size_t)b * SEQ;
        float sc = 0.f;
        for (int t = lane; t < SEQ; t += 64) {
            int   tg = tgb[t];
            float mt = mkb[t];
            sc += emb[t * NT + tg] * mt;
            if (t >= 1) sc += transitions[tgb[t - 1] * NT + tg] * mt;
        }
#pragma unroll
        for (int o = 32; o > 0; o >>= 1) sc += __shfl_down(sc, o, 64);
        if (lane == 0) atomicAdd(out, -sc * (1.0f / NBATCH));
        return;
    }

    // ---------------- recurrence blocks ----------------
    __shared__ __align__(16) float ring[RING * SLOT_F32];   // 36864 B
    __shared__ __align__(16) uint4 A_lds[32][64];           // 32768 B: [kt*8+m][lane]
    __shared__ int readyf[RING];
    __shared__ int freef[RING];

    const int wid   = tid >> 6;
    const int lane  = tid & 63;
    const int bbase = blk * 16;
    const int g     = lane >> 4;   // 0..3
    const int c     = lane & 15;   // batch column / tag-within-16

    if (tid == 0) {
#pragma unroll
        for (int i = 0; i < RING; ++i) { readyf[i] = -1; freef[i] = -1; }
    }

    // ---- cooperative A init: expT, tau-permuted k-rows, fragment-order in LDS.
    // B slot (kt, k=8g+e) carries tag tau = 16*(2kt+(e>>2)) + 4g + (e&3), which
    // is where the D->cvt_pk words land, so B is recycled D (no LDS for gamma).
    // Wave wid computes m = 2*wid, 2*wid+1.
#pragma unroll
    for (int dm = 0; dm < 2; ++dm) {
        int m = 2 * wid + dm;
        int jj = 16 * m + c;
#pragma unroll
        for (int kt = 0; kt < 4; ++kt) {
            uint32_t w[4];
#pragma unroll
            for (int wi = 0; wi < 4; ++wi) {
                int T0 = 16 * (2 * kt + (wi >> 1)) + 4 * g + 2 * (wi & 1);
                float f0 = __expf(transitions[T0 * NT + jj]);
                float f1 = __expf(transitions[(T0 + 1) * NT + jj]);
                asm("v_cvt_pk_bf16_f32 %0, %1, %2" : "=v"(w[wi]) : "v"(f0), "v"(f1));
            }
            A_lds[kt * 8 + m][lane] = make_uint4(w[0], w[1], w[2], w[3]);
        }
    }
    __syncthreads();

    volatile int* vready = readyf;
    volatile int* vfree  = freef;

    if (wid != 0) {
        // ---------- producers: steps t ≡ wid-1 (mod 3), exp(E_t) -> ring ----------
        const int bp = lane >> 2;     // batch 0..15
        const int tq = lane & 3;      // tag quarter (32 tags)
        const float* ebase = emissions + ((size_t)(bbase + bp) * SEQ) * NT + tq * 32;
        const int t0 = wid - 1;

#define PLOAD(Lx, t_) do { \
        const float* ep_ = ebase + (size_t)(t_) * NT; \
        _Pragma("unroll") for (int u = 0; u < 8; ++u) \
            Lx[u] = *(const float4*)(ep_ + u * 4); \
    } while (0)

#define PPROC(Lx, t_) do { \
        float4 W_[8]; \
        _Pragma("unroll") for (int u = 0; u < 8; ++u) { \
            W_[u].x = __expf(Lx[u].x); W_[u].y = __expf(Lx[u].y); \
            W_[u].z = __expf(Lx[u].z); W_[u].w = __expf(Lx[u].w); } \
        int s_ = (t_) & (RING - 1); \
        while (vfree[s_] < (t_) - RING) { __builtin_amdgcn_s_sleep(1); } \
        asm volatile("" ::: "memory"); \
        float* sp_ = ring + s_ * SLOT_F32; \
        _Pragma("unroll") for (int q = 0; q < 8; ++q) { \
            int a_ = (16 * (q & 3) + bp) * 36 + 8 * tq + 4 * (q >> 2); \
            *(float4*)(sp_ + a_) = W_[q]; } \
        asm volatile("s_waitcnt lgkmcnt(0)"); \
        if (lane == 0) vready[s_] = (t_); \
    } while (0)

        float4 L0[8], L1[8];
        PLOAD(L0, t0);
        PLOAD(L1, t0 + 3);

        for (int tt = t0; tt < SEQ; tt += 6) {
            PPROC(L0, tt);
            if (tt + 6 < SEQ) PLOAD(L0, tt + 6);
            if (tt + 3 < SEQ) {
                PPROC(L1, tt + 3);
                if (tt + 9 < SEQ) PLOAD(L1, tt + 9);
            }
        }
        return;
    }

    // ---------- consumer wave: the serial chain ----------
    const float* mbase = mask + (size_t)(bbase + c) * SEQ;

    // t = 0: gamma0 = exp(E0), straight from slot 0 into B fragments
    B8 Bf[4];
    {
        while (vready[0] < 0) {}
        asm volatile("" ::: "memory");
        const float* slot = ring + lane * 36;
        uint32_t pk[8][2];
#pragma unroll
        for (int m = 0; m < 8; ++m) {
            float4 e4 = *(const float4*)(slot + 4 * m);
            asm("v_cvt_pk_bf16_f32 %0, %1, %2" : "=v"(pk[m][0]) : "v"(e4.x), "v"(e4.y));
            asm("v_cvt_pk_bf16_f32 %0, %1, %2" : "=v"(pk[m][1]) : "v"(e4.z), "v"(e4.w));
        }
#pragma unroll
        for (int kt = 0; kt < 4; ++kt)
            Bf[kt].u4 = make_uint4(pk[2*kt][0], pk[2*kt][1], pk[2*kt+1][0], pk[2*kt+1][1]);
        asm volatile("s_waitcnt lgkmcnt(0)");
        if (lane == 0) vfree[0] = 0;
    }
    while (vready[1] < 1) {}
    asm volatile("" ::: "memory");

    int   kSum   = 0;
    float mt_cur = mbase[1];
    const f32x4v zero4 = {0.f, 0.f, 0.f, 0.f};

    for (int t = 1; t < SEQ; ++t) {
        const int s = t & (RING - 1);
        const float* slot = ring + s * SLOT_F32 + lane * 36;

        // rescale factor from PREVIOUS gamma's tag0 (off the critical path)
        const bool resc = ((t & 3) == 0);
        int   kk  = 0;
        float rcf = 1.0f;
        if (resc) {
            int v = __builtin_amdgcn_ds_bpermute(c << 2, (int)Bf[0].u4.x);
            int ebits = (v >> 7) & 0xff;          // bf16 exponent of gamma[0]
            kk  = ebits - 127;
            rcf = __uint_as_float((uint32_t)(254 - ebits) << 23);  // 2^{-kk}
        }

        // 32 MFMAs, kt-major, A fragments streamed from LDS (conflict-free,
        // lane-linear). Compiler pipelines ds_read -> MFMA with counted lgkmcnt.
        f32x4v acc[8];
        {
            B8 a[8];
#pragma unroll
            for (int m = 0; m < 8; ++m) a[m].u4 = A_lds[m][lane];
#pragma unroll
            for (int m = 0; m < 8; ++m)
                acc[m] = __builtin_amdgcn_mfma_f32_16x16x32_bf16(a[m].s8, Bf[0].s8, zero4, 0, 0, 0);
        }
#pragma unroll
        for (int kt = 1; kt < 4; ++kt) {
            B8 a[8];
#pragma unroll
            for (int m = 0; m < 8; ++m) a[m].u4 = A_lds[kt * 8 + m][lane];
#pragma unroll
            for (int m = 0; m < 8; ++m)
                acc[m] = __builtin_amdgcn_mfma_f32_16x16x32_bf16(a[m].s8, Bf[kt].s8, acc[m], 0, 0, 0);
        }

        // exp(E_t) reads (slot confirmed last iteration); complete under MFMA drain
        float4 e4[8];
#pragma unroll
        for (int m = 0; m < 8; ++m) e4[m] = *(const float4*)(slot + 4 * m);

        // poll next slot while the MFMA pipe drains
        if (t + 1 < SEQ) {
            while (vready[(t + 1) & (RING - 1)] < t + 1) {}
            asm volatile("" ::: "memory");
        }

        float mt = mt_cur;
        mt_cur = mbase[t + 1 < SEQ ? t + 1 : SEQ - 1];
        const bool upd = (mt != 0.0f);
        if (resc && upd) kSum += kk;

        // epilogue: gamma_new = D * expE (* rc) -> bf16 pairs -> next B frags
        uint32_t pk[8][2];
#pragma unroll
        for (int m = 0; m < 8; ++m) {
            float4 e = e4[m];
            if (resc) { e.x *= rcf; e.y *= rcf; e.z *= rcf; e.w *= rcf; }
            float x0 = acc[m][0] * e.x, x1 = acc[m][1] * e.y;
            float x2 = acc[m][2] * e.z, x3 = acc[m][3] * e.w;
            asm("v_cvt_pk_bf16_f32 %0, %1, %2" : "=v"(pk[m][0]) : "v"(x0), "v"(x1));
            asm("v_cvt_pk_bf16_f32 %0, %1, %2" : "=v"(pk[m][1]) : "v"(x2), "v"(x3));
        }
#pragma unroll
        for (int kt = 0; kt < 4; ++kt) {
            uint4 nb = make_uint4(pk[2*kt][0], pk[2*kt][1], pk[2*kt+1][0], pk[2*kt+1][1]);
            if (upd) Bf[kt].u4 = nb;     // masked batches keep old gamma
        }

        asm volatile("s_waitcnt lgkmcnt(0)");
        if (lane == 0) vfree[s] = t;
    }

    // logZ per batch: log(sum_tags gamma) + kSum*ln2
    float ssum = 0.f;
#pragma unroll
    for (int kt = 0; kt < 4; ++kt) {
        uint32_t uu[4] = {Bf[kt].u4.x, Bf[kt].u4.y, Bf[kt].u4.z, Bf[kt].u4.w};
#pragma unroll
        for (int k = 0; k < 4; ++k) {
            ssum += __uint_as_float(uu[k] << 16);
            ssum += __uint_as_float(uu[k] & 0xffff0000u);
        }
    }
    ssum += __shfl_xor(ssum, 16, 64);
    ssum += __shfl_xor(ssum, 32, 64);
    if (lane < 16) {
        float logZ = __logf(ssum) + (float)kSum * 0.69314718055994531f;
        atomicAdd(out, logZ * (1.0f / NBATCH));
    }
}

extern "C" void kernel_launch(void* const* d_in, const int* in_sizes, int n_in,
                              void* d_out, int out_size, void* d_ws, size_t ws_size,
                              hipStream_t stream) {
    const float* emissions   = (const float*)d_in[0];
    const float* transitions = (const float*)d_in[1];
    const int*   tags        = (const int*)d_in[2];
    const float* mask        = (const float*)d_in[3];
    float*       out         = (float*)d_out;

    hipMemsetAsync(out, 0, sizeof(float), stream);
    crf_kernel<<<80, 256, 0, stream>>>(emissions, transitions, tags, mask, out);
}

// Round 6
// 718.292 us; speedup vs baseline: 1.3401x; 1.3401x over previous
//
#include <hip/hip_runtime.h>
#include <stdint.h>

#define SEQ      1024
#define NT       128
#define NBATCH   256
#define RING     4
#define SLOT_F32 (64 * 36)   // per-slot: 64 lanes x (32 floats + 4 pad)

typedef float f32x4v __attribute__((ext_vector_type(4)));
using short8 = __attribute__((ext_vector_type(8))) short;
union B8 { uint4 u4; short8 s8; };

// blocks 0..15: recurrence (16 batches each; waves 0,1 = consumers (tag halves),
//               waves 2,3 = producers (step parity))
// blocks 16..79: score gathers (4 batches each, 1 wave per batch)
__global__ __launch_bounds__(256, 1) void crf_kernel(
    const float* __restrict__ emissions,   // [B, SEQ, NT]
    const float* __restrict__ transitions, // [NT, NT]
    const int*   __restrict__ tags,        // [B, SEQ]
    const float* __restrict__ mask,        // [B, SEQ]
    float* __restrict__ out)               // [1]
{
    const int blk = blockIdx.x;
    const int tid = threadIdx.x;

    if (blk >= 16) {
        // ---------------- score blocks ----------------
        int b    = (blk - 16) * 4 + (tid >> 6);
        int lane = tid & 63;
        const float* emb = emissions + (size_t)b * SEQ * NT;
        const int*   tgb = tags + (size_t)b * SEQ;
        const float* mkb = mask + (size_t)b * SEQ;
        float sc = 0.f;
        for (int t = lane; t < SEQ; t += 64) {
            int   tg = tgb[t];
            float mt = mkb[t];
            sc += emb[t * NT + tg] * mt;
            if (t >= 1) sc += transitions[tgb[t - 1] * NT + tg] * mt;
        }
#pragma unroll
        for (int o = 32; o > 0; o >>= 1) sc += __shfl_down(sc, o, 64);
        if (lane == 0) atomicAdd(out, -sc * (1.0f / NBATCH));
        return;
    }

    // ---------------- recurrence blocks ----------------
    __shared__ __align__(16) float ring[RING * SLOT_F32];   // 36864 B
    __shared__ __align__(16) uint4 xbuf[2][2][2][64];       // 8192 B [par][wave][frag][lane]
    __shared__ int vreadyA[RING];
    __shared__ int cflagA[2];
    __shared__ int vfreeA[2];

    const int wid   = tid >> 6;
    const int lane  = tid & 63;
    const int bbase = blk * 16;

    if (tid == 0) {
#pragma unroll
        for (int i = 0; i < RING; ++i) vreadyA[i] = -1;
        cflagA[0] = cflagA[1] = -1;
        vfreeA[0] = vfreeA[1] = -1;
    }
    __syncthreads();

    volatile int* vready = vreadyA;
    volatile int* vcf    = cflagA;
    volatile int* vfr    = vfreeA;

    if (wid >= 2) {
        // ---------- producers: steps t ≡ wid-2 (mod 2), exp(E_t) -> ring ----------
        const int bp = lane >> 2;     // batch 0..15
        const int tq = lane & 3;      // tag quarter (32 tags)
        const float* ebase = emissions + ((size_t)(bbase + bp) * SEQ) * NT + tq * 32;
        const int t0 = wid - 2;

#define PLOAD(Lx, t_) do { \
        const float* ep_ = ebase + (size_t)(t_) * NT; \
        _Pragma("unroll") for (int u = 0; u < 8; ++u) \
            Lx[u] = *(const float4*)(ep_ + u * 4); \
    } while (0)

#define PPROC(Lx, t_) do { \
        float4 W_[8]; \
        _Pragma("unroll") for (int u = 0; u < 8; ++u) { \
            W_[u].x = __expf(Lx[u].x); W_[u].y = __expf(Lx[u].y); \
            W_[u].z = __expf(Lx[u].z); W_[u].w = __expf(Lx[u].w); } \
        int s_ = (t_) & (RING - 1); \
        while (vfr[0] < (t_) - RING || vfr[1] < (t_) - RING) \
            { __builtin_amdgcn_s_sleep(1); } \
        asm volatile("" ::: "memory"); \
        float* sp_ = ring + s_ * SLOT_F32; \
        _Pragma("unroll") for (int q = 0; q < 8; ++q) { \
            int a_ = (16 * (q & 3) + bp) * 36 + 8 * tq + 4 * (q >> 2); \
            *(float4*)(sp_ + a_) = W_[q]; } \
        asm volatile("s_waitcnt lgkmcnt(0)"); \
        if (lane == 0) vready[s_] = (t_); \
    } while (0)

        float4 L0[8], L1[8];
        PLOAD(L0, t0);
        PLOAD(L1, t0 + 2);

        for (int tt = t0; tt < SEQ; tt += 4) {
            PPROC(L0, tt);
            if (tt + 4 < SEQ) PLOAD(L0, tt + 4);
            if (tt + 2 < SEQ) {
                PPROC(L1, tt + 2);
                if (tt + 6 < SEQ) PLOAD(L1, tt + 6);
            }
        }
        return;
    }

    // ---------- consumer wave w: owns output tags [64w, 64w+64) ----------
    const int w = wid;
    const int g = lane >> 4;   // 0..3
    const int c = lane & 15;   // batch column

    // A-half = expT rows for m = 4w+m_loc, tau-permuted k-rows, in registers.
    // tau(kt, 8g+e) = 16*(2kt+(e>>2)) + 4g + (e&3): D->cvt_pk words land exactly
    // in B-fragment order, so B is recycled D. Wave w's D = Bf[2w], Bf[2w+1].
    uint4 A[4][4];
#pragma unroll
    for (int ml = 0; ml < 4; ++ml) {
        int jj = 16 * (4 * w + ml) + c;
#pragma unroll
        for (int kt = 0; kt < 4; ++kt) {
            uint32_t wv[4];
#pragma unroll
            for (int wi = 0; wi < 4; ++wi) {
                int T0 = 16 * (2 * kt + (wi >> 1)) + 4 * g + 2 * (wi & 1);
                float f0 = __expf(transitions[T0 * NT + jj]);
                float f1 = __expf(transitions[(T0 + 1) * NT + jj]);
                asm("v_cvt_pk_bf16_f32 %0, %1, %2" : "=v"(wv[wi]) : "v"(f0), "v"(f1));
            }
            A[ml][kt] = make_uint4(wv[0], wv[1], wv[2], wv[3]);
        }
    }

    const float* mbase = mask + (size_t)(bbase + c) * SEQ;
    const f32x4v zero4 = {0.f, 0.f, 0.f, 0.f};

    // t = 0: own half of gamma0 = exp(E0) from slot 0
    B8 Bown[2];
    {
        while (vready[0] < 0) {}
        asm volatile("" ::: "memory");
        const float* slot = ring + lane * 36 + 16 * w;
        uint32_t pk[4][2];
#pragma unroll
        for (int ml = 0; ml < 4; ++ml) {
            float4 e4 = *(const float4*)(slot + 4 * ml);
            asm("v_cvt_pk_bf16_f32 %0, %1, %2" : "=v"(pk[ml][0]) : "v"(e4.x), "v"(e4.y));
            asm("v_cvt_pk_bf16_f32 %0, %1, %2" : "=v"(pk[ml][1]) : "v"(e4.z), "v"(e4.w));
        }
        Bown[0].u4 = make_uint4(pk[0][0], pk[0][1], pk[1][0], pk[1][1]);
        Bown[1].u4 = make_uint4(pk[2][0], pk[2][1], pk[3][0], pk[3][1]);
        xbuf[0][w][0][lane] = Bown[0].u4;
        xbuf[0][w][1][lane] = Bown[1].u4;
        asm volatile("s_waitcnt lgkmcnt(0)");
        if (lane == 0) { vfr[w] = 0; vcf[w] = 0; }
    }

    // pre-issue step-1 inputs
    B8 pb[2];
    float4 e4[4];
    {
        while (vready[1] < 1) {}
        asm volatile("" ::: "memory");
        while (vcf[1 - w] < 0) {}
        asm volatile("" ::: "memory");
        pb[0].u4 = xbuf[0][1 - w][0][lane];
        pb[1].u4 = xbuf[0][1 - w][1][lane];
        const float* slot = ring + SLOT_F32 + lane * 36 + 16 * w;
#pragma unroll
        for (int ml = 0; ml < 4; ++ml) e4[ml] = *(const float4*)(slot + 4 * ml);
    }

    int   kSum   = 0;
    float mt_cur = mbase[1];
    const int ko0 = 2 * w, ko1 = 2 * w + 1;          // own kt tiles
    const int kp0 = 2 * (1 - w), kp1 = 2 * (1 - w) + 1; // partner kt tiles

    for (int t = 1; t < SEQ; ++t) {
        // rescale factor from current gamma's tag0 (tile kt=0)
        const bool resc = ((t & 3) == 0);
        int   kk  = 0;
        float rcf = 1.0f;
        if (resc) {
            uint32_t b0 = (w == 0) ? Bown[0].u4.x : pb[0].u4.x;
            int v = __builtin_amdgcn_ds_bpermute(c << 2, (int)b0);
            int ebits = (v >> 7) & 0xff;
            kk  = ebits - 127;
            rcf = __uint_as_float((uint32_t)(254 - ebits) << 23);
        }

        // 16 MFMAs: own tiles first (pure reg), partner tiles gated on LDS reads
        f32x4v acc[4];
#pragma unroll
        for (int ml = 0; ml < 4; ++ml)
            acc[ml] = __builtin_amdgcn_mfma_f32_16x16x32_bf16(((B8*)&A[ml][ko0])->s8, Bown[0].s8, zero4, 0, 0, 0);
#pragma unroll
        for (int ml = 0; ml < 4; ++ml)
            acc[ml] = __builtin_amdgcn_mfma_f32_16x16x32_bf16(((B8*)&A[ml][ko1])->s8, Bown[1].s8, acc[ml], 0, 0, 0);
#pragma unroll
        for (int ml = 0; ml < 4; ++ml)
            acc[ml] = __builtin_amdgcn_mfma_f32_16x16x32_bf16(((B8*)&A[ml][kp0])->s8, pb[0].s8, acc[ml], 0, 0, 0);
#pragma unroll
        for (int ml = 0; ml < 4; ++ml)
            acc[ml] = __builtin_amdgcn_mfma_f32_16x16x32_bf16(((B8*)&A[ml][kp1])->s8, pb[1].s8, acc[ml], 0, 0, 0);

        float mt = mt_cur;
        mt_cur = mbase[t + 1 < SEQ ? t + 1 : SEQ - 1];
        const bool upd = (mt != 0.0f);
        if (resc && upd) kSum += kk;

        // epilogue: own-half gamma_new = D * expE (* rc) -> bf16 -> next Bown
        uint32_t pk[4][2];
#pragma unroll
        for (int ml = 0; ml < 4; ++ml) {
            float4 e = e4[ml];
            if (resc) { e.x *= rcf; e.y *= rcf; e.z *= rcf; e.w *= rcf; }
            float x0 = acc[ml][0] * e.x, x1 = acc[ml][1] * e.y;
            float x2 = acc[ml][2] * e.z, x3 = acc[ml][3] * e.w;
            asm("v_cvt_pk_bf16_f32 %0, %1, %2" : "=v"(pk[ml][0]) : "v"(x0), "v"(x1));
            asm("v_cvt_pk_bf16_f32 %0, %1, %2" : "=v"(pk[ml][1]) : "v"(x2), "v"(x3));
        }
        {
            uint4 nb0 = make_uint4(pk[0][0], pk[0][1], pk[1][0], pk[1][1]);
            uint4 nb1 = make_uint4(pk[2][0], pk[2][1], pk[3][0], pk[3][1]);
            if (upd) { Bown[0].u4 = nb0; Bown[1].u4 = nb1; }
        }

        // publish own half + free e-slot
        const int par = t & 1;
        xbuf[par][w][0][lane] = Bown[0].u4;
        xbuf[par][w][1][lane] = Bown[1].u4;
        asm volatile("s_waitcnt lgkmcnt(0)");
        if (lane == 0) { vfr[w] = t; vcf[w] = t; }

        // pre-issue next step's inputs (partner half + e4) so they drain
        // under next step's own-tile MFMAs
        if (t + 1 < SEQ) {
            while (vready[(t + 1) & (RING - 1)] < t + 1) {}
            asm volatile("" ::: "memory");
            while (vcf[1 - w] < t) {}
            asm volatile("" ::: "memory");
            pb[0].u4 = xbuf[par][1 - w][0][lane];
            pb[1].u4 = xbuf[par][1 - w][1][lane];
            const float* slot = ring + ((t + 1) & (RING - 1)) * SLOT_F32 + lane * 36 + 16 * w;
#pragma unroll
            for (int ml = 0; ml < 4; ++ml) e4[ml] = *(const float4*)(slot + 4 * ml);
        }
    }

    if (w == 1) return;

    // ---------- finale (wave 0): logZ = log(sum_tags gamma) + kSum*ln2 ----------
    while (vcf[1] < SEQ - 1) {}
    asm volatile("" ::: "memory");
    const int fpar = (SEQ - 1) & 1;
    uint4 q0 = xbuf[fpar][1][0][lane];
    uint4 q1 = xbuf[fpar][1][1][lane];

    float ssum = 0.f;
    uint32_t all_u[16] = {Bown[0].u4.x, Bown[0].u4.y, Bown[0].u4.z, Bown[0].u4.w,
                          Bown[1].u4.x, Bown[1].u4.y, Bown[1].u4.z, Bown[1].u4.w,
                          q0.x, q0.y, q0.z, q0.w, q1.x, q1.y, q1.z, q1.w};
#pragma unroll
    for (int k = 0; k < 16; ++k) {
        ssum += __uint_as_float(all_u[k] << 16);
        ssum += __uint_as_float(all_u[k] & 0xffff0000u);
    }
    ssum += __shfl_xor(ssum, 16, 64);
    ssum += __shfl_xor(ssum, 32, 64);
    if (lane < 16) {
        float logZ = __logf(ssum) + (float)kSum * 0.69314718055994531f;
        atomicAdd(out, logZ * (1.0f / NBATCH));
    }
}

extern "C" void kernel_launch(void* const* d_in, const int* in_sizes, int n_in,
                              void* d_out, int out_size, void* d_ws, size_t ws_size,
                              hipStream_t stream) {
    const float* emissions   = (const float*)d_in[0];
    const float* transitions = (const float*)d_in[1];
    const int*   tags        = (const int*)d_in[2];
    const float* mask        = (const float*)d_in[3];
    float*       out         = (float*)d_out;

    hipMemsetAsync(out, 0, sizeof(float), stream);
    crf_kernel<<<80, 256, 0, stream>>>(emissions, transitions, tags, mask, out);
}

// Round 7
// 298.300 us; speedup vs baseline: 3.2268x; 2.4080x over previous
//
#include <hip/hip_runtime.h>
#include <stdint.h>

#define SEQ      1024
#define NT       128
#define NBATCH   256
#define MID      512          // fwd -> alpha_512, bwd -> beta_512
#define WS_STRIDE 132         // 128 floats + kSum

typedef float v2f __attribute__((ext_vector_type(2)));

// blocks [0,256):    forward chains,  batch = blk       (steps 1..512)
// blocks [256,512):  backward chains, batch = blk-256   (steps 1023..513)
// blocks [512,576):  score gathers (4 batches each)
__global__ __launch_bounds__(256) void crf_chains(
    const float* __restrict__ emissions,   // [B, SEQ, NT]
    const float* __restrict__ transitions, // [NT, NT]
    const int*   __restrict__ tags,        // [B, SEQ]
    const float* __restrict__ mask,        // [B, SEQ]
    float* __restrict__ out,               // [1]
    float* __restrict__ ws)                // [2*256*132]
{
    const int blk = blockIdx.x;
    const int tid = threadIdx.x;

    if (blk >= 2 * NBATCH) {
        // ---------------- score blocks ----------------
        int b    = (blk - 2 * NBATCH) * 4 + (tid >> 6);
        int lane = tid & 63;
        const float* emb = emissions + (size_t)b * SEQ * NT;
        const int*   tgb = tags + (size_t)b * SEQ;
        const float* mkb = mask + (size_t)b * SEQ;
        float sc = 0.f;
        for (int t = lane; t < SEQ; t += 64) {
            int   tg = tgb[t];
            float mt = mkb[t];
            sc += emb[t * NT + tg] * mt;
            if (t >= 1) sc += transitions[tgb[t - 1] * NT + tg] * mt;
        }
#pragma unroll
        for (int o = 32; o > 0; o >>= 1) sc += __shfl_down(sc, o, 64);
        if (lane == 0) atomicAdd(out, -sc * (1.0f / NBATCH));
        return;
    }

    const int jt = tid >> 1;   // tag owned by this thread-pair
    const int q  = tid & 1;    // which 64-wide slice of the sum

    __shared__ __align__(16) float buf[2][NT];

#define MATVEC(Wt, S_) do { \
        v2f s0={0,0}, s1={0,0}, s2={0,0}, s3={0,0}; \
        _Pragma("unroll") \
        for (int cc = 0; cc < 8; ++cc) { \
            float4 ga = *(const float4*)(gp + cc * 8); \
            float4 gb = *(const float4*)(gp + cc * 8 + 4); \
            v2f a0 = {ga.x, ga.y}, a1 = {ga.z, ga.w}; \
            v2f b0 = {gb.x, gb.y}, b1 = {gb.z, gb.w}; \
            s0 = __builtin_elementwise_fma(Wt[4*cc+0], a0, s0); \
            s1 = __builtin_elementwise_fma(Wt[4*cc+1], a1, s1); \
            s2 = __builtin_elementwise_fma(Wt[4*cc+2], b0, s2); \
            s3 = __builtin_elementwise_fma(Wt[4*cc+3], b1, s3); \
        } \
        S_ = ((s0.x+s0.y)+(s1.x+s1.y)) + ((s2.x+s2.y)+(s3.x+s3.y)); \
        S_ += __shfl_xor(S_, 1, 64); \
    } while (0)

    if (blk < NBATCH) {
        // ---------------- forward chain: alpha, steps t = 1..MID ----------------
        const int b = blk;
        const float* emb = emissions + (size_t)b * SEQ * NT;
        const float* mkb = mask + (size_t)b * SEQ;

        // expT column jt, rows q*64.., as 32 float2 in regs
        v2f colT[32];
#pragma unroll
        for (int k = 0; k < 32; ++k) {
            int i = q * 64 + 2 * k;
            colT[k].x = __expf(transitions[(i    ) * NT + jt]);
            colT[k].y = __expf(transitions[(i + 1) * NT + jt]);
        }
        if (q == 0) buf[0][jt] = __expf(emb[jt]);
        __syncthreads();

        int kSum = 0, p = 0;
        float Ecur = emb[(1 + q) * NT + jt];
        float M0 = mkb[1], M1 = mkb[2];

        for (int t0 = 1; t0 < MID; t0 += 2) {      // steps t0, t0+1 (both <= MID)
            float En  = emb[(t0 + 2 + q) * NT + jt];       // <= 514, in bounds
            float Mn0 = mkb[t0 + 2];
            float Mn1 = mkb[t0 + 3];
#pragma unroll
            for (int dq = 0; dq < 2; ++dq) {
                float mt = dq ? M1 : M0;
                if (mt != 0.0f) {
                    float c0 = buf[p][0];
                    const float* gp = &buf[p][q * 64];
                    float s;
                    MATVEC(colT, s);
                    int k = (int)(__float_as_uint(c0) >> 23) - 127;
                    float rc = __uint_as_float((uint32_t)(127 - k) << 23);
                    kSum += k;
                    if (q == dq) buf[p ^ 1][jt] = s * rc * __expf(Ecur);
                    p ^= 1;
                }
                __syncthreads();
            }
            Ecur = En; M0 = Mn0; M1 = Mn1;
        }
        float* wsb = ws + (size_t)b * WS_STRIDE;
        if (q == 0)   wsb[jt]  = buf[p][jt];     // alpha_MID (pow2-scaled)
        if (tid == 0) wsb[128] = (float)kSum;
        return;
    }

    // ---------------- backward chain: beta, steps t = SEQ-1 .. MID+1 ----------------
    {
        const int b = blk - NBATCH;
        const float* emb = emissions + (size_t)b * SEQ * NT;
        const float* mkb = mask + (size_t)b * SEQ;

        // expT row jt, cols q*64.. (contiguous), as 32 float2 in regs
        v2f rowT[32];
#pragma unroll
        for (int k = 0; k < 32; ++k) {
            int jj = q * 64 + 2 * k;
            rowT[k].x = __expf(transitions[jt * NT + jj]);
            rowT[k].y = __expf(transitions[jt * NT + jj + 1]);
        }
        // w_{T-1} = expE_{T-1} * beta_{T-1}(=1)
        if (q == 0) buf[0][jt] = __expf(emb[(size_t)(SEQ - 1) * NT + jt]);
        __syncthreads();

        int   kSum = 0, p = 0;
        float beta = 1.0f;
        float Ecur = emb[(size_t)(SEQ - 2 - q) * NT + jt];   // E[1022-q]
        float M0 = mkb[SEQ - 1], M1 = mkb[SEQ - 2];

        for (int t0 = SEQ - 1; t0 >= MID + 1; t0 -= 2) {   // steps t0, t0-1
            int tnE = t0 - 3 - q; if (tnE < 0) tnE = 0;
            float En  = emb[(size_t)tnE * NT + jt];
            int tm0 = t0 - 2; if (tm0 < 0) tm0 = 0;
            int tm1 = t0 - 3; if (tm1 < 0) tm1 = 0;
            float Mn0 = mkb[tm0], Mn1 = mkb[tm1];
#pragma unroll
            for (int dq = 0; dq < 2; ++dq) {
                int t = t0 - dq;
                if (t >= MID + 1) {
                    float mt = dq ? M1 : M0;
                    float c0 = buf[p][0];
                    const float* gp = &buf[p][q * 64];
                    float s;
                    MATVEC(rowT, s);
                    int k = (int)(__float_as_uint(c0) >> 23) - 127;
                    float rc = __uint_as_float((uint32_t)(127 - k) << 23);
                    kSum += k;
                    float bn = (mt != 0.0f) ? s * rc : beta * rc;
                    if (q == dq) buf[p ^ 1][jt] = bn * __expf(Ecur);
                    beta = bn; p ^= 1;
                    __syncthreads();
                }
            }
            Ecur = En; M0 = Mn0; M1 = Mn1;
        }
        float* wsb = ws + (size_t)(NBATCH + b) * WS_STRIDE;
        if (q == 0)   wsb[jt]  = beta;           // beta_MID (pow2-scaled)
        if (tid == 0) wsb[128] = (float)kSum;
        return;
    }
}

// Z = sum_i alpha_MID[i] * beta_MID[i] * 2^(kF+kB)
__global__ __launch_bounds__(64) void crf_combine(
    const float* __restrict__ ws, float* __restrict__ out)
{
    int b    = blockIdx.x;
    int lane = threadIdx.x;
    const float* af = ws + (size_t)b * WS_STRIDE;
    const float* bf = ws + (size_t)(NBATCH + b) * WS_STRIDE;
    float d = af[lane] * bf[lane] + af[lane + 64] * bf[lane + 64];
#pragma unroll
    for (int o = 32; o > 0; o >>= 1) d += __shfl_down(d, o, 64);
    if (lane == 0) {
        float logZ = __logf(d) + (af[128] + bf[128]) * 0.69314718055994531f;
        atomicAdd(out, logZ * (1.0f / NBATCH));
    }
}

extern "C" void kernel_launch(void* const* d_in, const int* in_sizes, int n_in,
                              void* d_out, int out_size, void* d_ws, size_t ws_size,
                              hipStream_t stream) {
    const float* emissions   = (const float*)d_in[0];
    const float* transitions = (const float*)d_in[1];
    const int*   tags        = (const int*)d_in[2];
    const float* mask        = (const float*)d_in[3];
    float*       out         = (float*)d_out;
    float*       ws          = (float*)d_ws;

    hipMemsetAsync(out, 0, sizeof(float), stream);
    crf_chains<<<2 * NBATCH + 64, 256, 0, stream>>>(
        emissions, transitions, tags, mask, out, ws);
    crf_combine<<<NBATCH, 64, 0, stream>>>(ws, out);
}